// Round 1
// baseline (19387.859 us; speedup 1.0000x reference)
//
#include <hip/hip_runtime.h>
#include <stdint.h>

// ---------------- constants ----------------
#define HID   1024          // H
#define B3H   3072          // 3H
#define BSZ   256           // batch
#define TLEN  128           // seq len
#define VOC   512
#define EMB   512

typedef unsigned short u16;
typedef short bf16x8 __attribute__((ext_vector_type(8)));
typedef float f32x4  __attribute__((ext_vector_type(4)));

__device__ __forceinline__ float bf2f(u16 u) {
    union { float f; uint32_t i; } c; c.i = ((uint32_t)u) << 16; return c.f;
}
__device__ __forceinline__ u16 f2bf(float f) {
    union { float f; uint32_t i; } c; c.f = f;
    uint32_t u = c.i;
    return (u16)((u + 0x7FFFu + ((u >> 16) & 1u)) >> 16);   // RNE
}

// ---------------- tiny utility kernels ----------------
__global__ void k_convert(const float* __restrict__ in, u16* __restrict__ out, int n) {
    int i = (blockIdx.x * 256 + threadIdx.x) * 4;
    if (i >= n) return;
    float4 f = *(const float4*)(in + i);
    uint32_t lo = (uint32_t)f2bf(f.x) | ((uint32_t)f2bf(f.y) << 16);
    uint32_t hi = (uint32_t)f2bf(f.z) | ((uint32_t)f2bf(f.w) << 16);
    uint2 p; p.x = lo; p.y = hi;
    *(uint2*)(out + i) = p;
}
__global__ void k_zero_f32(float* p, int n) { int i = blockIdx.x * 256 + threadIdx.x; if (i < n) p[i] = 0.f; }
__global__ void k_zero_u16(u16* p, int n)   { int i = blockIdx.x * 256 + threadIdx.x; if (i < n) p[i] = 0;   }

// ---------------- MFMA tile helpers ----------------
// Wave computes a 16(M) x 64(N) strip.  A/W row-major bf16, C = A @ W^T.
// A frag: lane holds row (lane&15), k = (lane>>4)*8 + j  (8 contiguous bf16)
// D frag: col = lane&15, row = (lane>>4)*4 + reg   [m89-verified]
__device__ __forceinline__ void mfma16x64(const u16* __restrict__ Aw, int lda,
                                          const u16* __restrict__ Wt, int ldb,
                                          int kLen, f32x4 acc[4], int lane) {
    const int r = lane & 15, g = lane >> 4;
    const u16* ap = Aw + (size_t)r * lda + g * 8;
    for (int k = 0; k < kLen; k += 32) {
        bf16x8 a = *(const bf16x8*)(ap + k);
#pragma unroll
        for (int n = 0; n < 4; n++) {
            bf16x8 b = *(const bf16x8*)(Wt + (size_t)(n * 16 + r) * ldb + g * 8 + k);
            acc[n] = __builtin_amdgcn_mfma_f32_16x16x32_bf16(a, b, acc[n], 0, 0, 0);
        }
    }
}
__device__ __forceinline__ void store_f32(float* Cw, int ldc, const float* bias,
                                          const f32x4 acc[4], int lane) {
    int c = lane & 15, r0 = (lane >> 4) * 4;
#pragma unroll
    for (int n = 0; n < 4; n++)
#pragma unroll
        for (int r = 0; r < 4; r++) {
            float x = acc[n][r] + (bias ? bias[n * 16 + c] : 0.f);
            Cw[(size_t)(r0 + r) * ldc + n * 16 + c] = x;
        }
}

// ---------------- proj: X_all[t*B+b] = emb[tok] @ projW^T + projb (bf16 out) ----------------
__global__ void k_proj(const u16* __restrict__ emb_bf, const u16* __restrict__ projW_bf,
                       const float* __restrict__ projb, const int* __restrict__ target,
                       u16* __restrict__ X_all) {
    int tn = blockIdx.x * 64, tm = blockIdx.y * 64;
    int wid = threadIdx.x >> 6, lane = threadIdx.x & 63;
    int rr = lane & 15, g = lane >> 4;
    int rowg = tm + wid * 16 + rr;
    int t = rowg >> 8, b = rowg & 255;
    int tok = (t == 0) ? 0 : target[b * TLEN + t - 1];
    const u16* ap = emb_bf + (size_t)tok * EMB + g * 8;
    f32x4 acc[4];
#pragma unroll
    for (int n = 0; n < 4; n++) for (int q = 0; q < 4; q++) acc[n][q] = 0.f;
    for (int k = 0; k < EMB; k += 32) {
        bf16x8 a = *(const bf16x8*)(ap + k);
#pragma unroll
        for (int n = 0; n < 4; n++) {
            bf16x8 bb = *(const bf16x8*)(projW_bf + (size_t)(tn + n * 16 + rr) * EMB + g * 8 + k);
            acc[n] = __builtin_amdgcn_mfma_f32_16x16x32_bf16(a, bb, acc[n], 0, 0, 0);
        }
    }
    int c = lane & 15, r0 = (lane >> 4) * 4;
    u16* Cw = X_all + (size_t)(tm + wid * 16) * HID + tn;
#pragma unroll
    for (int n = 0; n < 4; n++)
#pragma unroll
        for (int q = 0; q < 4; q++)
            Cw[(size_t)(r0 + q) * HID + n * 16 + c] = f2bf(acc[n][q] + projb[tn + n * 16 + c]);
}

// ---------------- stage 1: gi0 + gh0..gh2 (4 batched GEMMs [256,1024]->[256,3072]) ----------------
__global__ void k_gates(const u16* __restrict__ X_all, const u16* __restrict__ h_bf,
                        const u16* __restrict__ Wih, const u16* __restrict__ Whh,
                        const float* __restrict__ bih, const float* __restrict__ bhh,
                        float* __restrict__ gi0, float* __restrict__ gh, int t) {
    int z = blockIdx.z;
    const u16* A; const u16* W; const float* bias; float* C;
    if (z == 0) { A = X_all + (size_t)t * BSZ * HID; W = Wih; bias = bih; C = gi0; }
    else {
        int i = z - 1;
        A = h_bf + (size_t)i * BSZ * HID;
        W = Whh + (size_t)i * B3H * HID;
        bias = bhh + i * B3H;
        C = gh + (size_t)i * BSZ * B3H;
    }
    int tn = blockIdx.x * 64, tm = blockIdx.y * 64;
    int wid = threadIdx.x >> 6, lane = threadIdx.x & 63;
    f32x4 acc[4];
#pragma unroll
    for (int n = 0; n < 4; n++) for (int q = 0; q < 4; q++) acc[n][q] = 0.f;
    mfma16x64(A + (size_t)(tm + wid * 16) * HID, HID, W + (size_t)tn * HID, HID, HID, acc, lane);
    store_f32(C + (size_t)(tm + wid * 16) * B3H + tn, B3H, bias + tn, acc, lane);
}

// ---------------- generic GEMM -> f32 (used for gi1 / gi2) ----------------
__global__ void k_gemm_f32(const u16* __restrict__ A, int lda, const u16* __restrict__ W, int ldb,
                           const float* __restrict__ bias, float* __restrict__ C, int ldc, int kLen) {
    int tn = blockIdx.x * 64, tm = blockIdx.y * 64;
    int wid = threadIdx.x >> 6, lane = threadIdx.x & 63;
    f32x4 acc[4];
#pragma unroll
    for (int n = 0; n < 4; n++) for (int q = 0; q < 4; q++) acc[n][q] = 0.f;
    mfma16x64(A + (size_t)(tm + wid * 16) * lda, lda, W + (size_t)tn * ldb, ldb, kLen, acc, lane);
    store_f32(C + (size_t)(tm + wid * 16) * ldc + tn, ldc, bias + tn, acc, lane);
}

// ---------------- fc1: relu(h2 @ fc1W^T + b) -> bf16 ----------------
__global__ void k_fc1(const u16* __restrict__ A, const u16* __restrict__ W,
                      const float* __restrict__ bias, u16* __restrict__ C) {
    int tn = blockIdx.x * 64, tm = blockIdx.y * 64;
    int wid = threadIdx.x >> 6, lane = threadIdx.x & 63;
    f32x4 acc[4];
#pragma unroll
    for (int n = 0; n < 4; n++) for (int q = 0; q < 4; q++) acc[n][q] = 0.f;
    mfma16x64(A + (size_t)(tm + wid * 16) * HID, HID, W + (size_t)tn * HID, HID, HID, acc, lane);
    int c = lane & 15, r0 = (lane >> 4) * 4;
    u16* Cw = C + (size_t)(tm + wid * 16) * 2048 + tn;
#pragma unroll
    for (int n = 0; n < 4; n++)
#pragma unroll
        for (int q = 0; q < 4; q++) {
            float x = acc[n][q] + bias[tn + n * 16 + c];
            Cw[(size_t)(r0 + q) * 2048 + n * 16 + c] = f2bf(fmaxf(x, 0.f));
        }
}

// ---------------- fc2 partial (K split in 8 chunks of 256) ----------------
__global__ void k_fc2(const u16* __restrict__ A, const u16* __restrict__ W, float* __restrict__ part) {
    int kc = blockIdx.z;
    int tn = blockIdx.x * 64, tm = blockIdx.y * 64;
    int wid = threadIdx.x >> 6, lane = threadIdx.x & 63;
    f32x4 acc[4];
#pragma unroll
    for (int n = 0; n < 4; n++) for (int q = 0; q < 4; q++) acc[n][q] = 0.f;
    mfma16x64(A + (size_t)(tm + wid * 16) * 2048 + kc * 256, 2048,
              W + (size_t)tn * 2048 + kc * 256, 2048, 256, acc, lane);
    store_f32(part + (size_t)kc * BSZ * VOC + (size_t)(tm + wid * 16) * VOC + tn, VOC, nullptr, acc, lane);
}

// ---------------- GRU elementwise + residual + LayerNorm (one WG per row) ----------------
__global__ void k_ew(int cell, int t, const float* __restrict__ gi, const float* __restrict__ ghall,
                     float* __restrict__ h_f32, u16* __restrict__ h_bf,
                     const u16* __restrict__ X_all,
                     const float* __restrict__ ln_s_all, const float* __restrict__ ln_b_all) {
    int b = blockIdx.x, tid = threadIdx.x;
    const float* gh = ghall + (size_t)cell * BSZ * B3H + (size_t)b * B3H;
    const float* gr = gi + (size_t)b * B3H;
    const float* hp = h_f32 + (size_t)cell * BSZ * HID + (size_t)b * HID;
    float v[4], s = 0.f, s2 = 0.f;
#pragma unroll
    for (int e = 0; e < 4; e++) {
        int j = e * 256 + tid;
        float r = 1.f / (1.f + expf(-(gr[j] + gh[j])));
        float z = 1.f / (1.f + expf(-(gr[HID + j] + gh[HID + j])));
        float n = tanhf(gr[2 * HID + j] + r * gh[2 * HID + j]);
        float xv = (cell == 0)
            ? bf2f(X_all[(size_t)t * BSZ * HID + (size_t)b * HID + j])
            : h_f32[(size_t)(cell - 1) * BSZ * HID + (size_t)b * HID + j];
        float val = (1.f - z) * n + z * hp[j] + xv;
        v[e] = val; s += val; s2 += val * val;
    }
    __shared__ float red[8];
    for (int o = 32; o > 0; o >>= 1) { s += __shfl_down(s, o); s2 += __shfl_down(s2, o); }
    int wid = tid >> 6, lane = tid & 63;
    if (lane == 0) { red[wid] = s; red[4 + wid] = s2; }
    __syncthreads();
    s = red[0] + red[1] + red[2] + red[3];
    s2 = red[4] + red[5] + red[6] + red[7];
    float mu = s * (1.f / HID);
    float var = s2 * (1.f / HID) - mu * mu;
    float inv = rsqrtf(var + 1e-5f);
    float* ho = h_f32 + (size_t)cell * BSZ * HID + (size_t)b * HID;
    u16* hb = h_bf + (size_t)cell * BSZ * HID + (size_t)b * HID;
    const float* lns = ln_s_all + cell * HID;
    const float* lnb = ln_b_all + cell * HID;
#pragma unroll
    for (int e = 0; e < 4; e++) {
        int j = e * 256 + tid;
        float o = (v[e] - mu) * inv * lns[j] + lnb[j];
        ho[j] = o; hb[j] = f2bf(o);
    }
}

// ---------------- logsumexp + target gather + accumulate ----------------
__global__ void k_lse(const float* __restrict__ part, const float* __restrict__ fc2b,
                      const int* __restrict__ target, int t,
                      float* __restrict__ acc, float* __restrict__ out) {
    int wid = threadIdx.x >> 6, lane = threadIdx.x & 63;
    int row = blockIdx.x * 4 + wid;
    float v[8];
#pragma unroll
    for (int e = 0; e < 8; e++) {
        int j = e * 64 + lane;
        float x = fc2b[j];
#pragma unroll
        for (int kc = 0; kc < 8; kc++) x += part[(size_t)kc * BSZ * VOC + (size_t)row * VOC + j];
        v[e] = x;
    }
    float m = v[0];
#pragma unroll
    for (int e = 1; e < 8; e++) m = fmaxf(m, v[e]);
    for (int o = 32; o > 0; o >>= 1) m = fmaxf(m, __shfl_xor(m, o));
    float s = 0.f;
#pragma unroll
    for (int e = 0; e < 8; e++) s += expf(v[e] - m);
    for (int o = 32; o > 0; o >>= 1) s += __shfl_xor(s, o);
    int tg = target[row * TLEN + t];
    float tv = 0.f;
#pragma unroll
    for (int e = 0; e < 8; e++) if (e * 64 + lane == tg) tv = v[e];
    for (int o = 32; o > 0; o >>= 1) tv += __shfl_xor(tv, o);
    float lse = m + logf(s);
    if (lane == 0) {
        float na = acc[row] + (tv - lse);
        acc[row] = na;
        if (t == TLEN - 1) out[row] = na;
    }
}

// ---------------- host ----------------
extern "C" void kernel_launch(void* const* d_in, const int* in_sizes, int n_in,
                              void* d_out, int out_size, void* d_ws, size_t ws_size,
                              hipStream_t stream) {
    const int*   target = (const int*)  d_in[0];
    const float* emb    = (const float*)d_in[1];
    const float* projW  = (const float*)d_in[2];
    const float* projb  = (const float*)d_in[3];
    const float* gWih   = (const float*)d_in[4];
    const float* gWhh   = (const float*)d_in[5];
    const float* gbih   = (const float*)d_in[6];
    const float* gbhh   = (const float*)d_in[7];
    const float* ln_s   = (const float*)d_in[8];
    const float* ln_b   = (const float*)d_in[9];
    const float* fc1W   = (const float*)d_in[10];
    const float* fc1b   = (const float*)d_in[11];
    const float* fc2W   = (const float*)d_in[12];
    const float* fc2b   = (const float*)d_in[13];
    float* out = (float*)d_out;

    char* ws = (char*)d_ws;
    size_t off = 0;
    auto alloc = [&](size_t bytes) { void* p = ws + off; off += (bytes + 511) & ~511ull; return p; };
    u16* emb_bf   = (u16*)alloc((size_t)VOC * EMB * 2);
    u16* projW_bf = (u16*)alloc((size_t)HID * EMB * 2);
    u16* Wih_bf   = (u16*)alloc((size_t)3 * B3H * HID * 2);
    u16* Whh_bf   = (u16*)alloc((size_t)3 * B3H * HID * 2);
    u16* fc1W_bf  = (u16*)alloc((size_t)2048 * HID * 2);
    u16* fc2W_bf  = (u16*)alloc((size_t)VOC * 2048 * 2);
    u16* X_all    = (u16*)alloc((size_t)TLEN * BSZ * HID * 2);
    float* h_f32  = (float*)alloc((size_t)3 * BSZ * HID * 4);
    u16* h_bf     = (u16*)alloc((size_t)3 * BSZ * HID * 2);
    float* gi0    = (float*)alloc((size_t)BSZ * B3H * 4);
    float* gh     = (float*)alloc((size_t)3 * BSZ * B3H * 4);
    float* giX    = (float*)alloc((size_t)BSZ * B3H * 4);
    u16* a1_bf    = (u16*)alloc((size_t)BSZ * 2048 * 2);
    float* part   = (float*)alloc((size_t)8 * BSZ * VOC * 4);
    float* accbuf = (float*)alloc((size_t)BSZ * 4);
    if (off > ws_size) return;   // workspace too small -> bench will show failure

    auto cvt = [&](const float* s, u16* d, int n) {
        k_convert<<<dim3((n / 4 + 255) / 256), 256, 0, stream>>>(s, d, n);
    };
    cvt(emb,   emb_bf,   VOC * EMB);
    cvt(projW, projW_bf, HID * EMB);
    cvt(gWih,  Wih_bf,   3 * B3H * HID);
    cvt(gWhh,  Whh_bf,   3 * B3H * HID);
    cvt(fc1W,  fc1W_bf,  2048 * HID);
    cvt(fc2W,  fc2W_bf,  VOC * 2048);
    k_zero_f32<<<dim3((3 * BSZ * HID + 255) / 256), 256, 0, stream>>>(h_f32, 3 * BSZ * HID);
    k_zero_u16<<<dim3((3 * BSZ * HID + 255) / 256), 256, 0, stream>>>(h_bf, 3 * BSZ * HID);
    k_zero_f32<<<dim3(1), 256, 0, stream>>>(accbuf, BSZ);

    // X_all: [T*B, 1024] = emb[tok] @ projW^T + projb
    k_proj<<<dim3(HID / 64, (TLEN * BSZ) / 64), 256, 0, stream>>>(emb_bf, projW_bf, projb, target, X_all);

    for (int t = 0; t < TLEN; t++) {
        k_gates<<<dim3(B3H / 64, BSZ / 64, 4), 256, 0, stream>>>(X_all, h_bf, Wih_bf, Whh_bf,
                                                                 gbih, gbhh, gi0, gh, t);
        k_ew<<<dim3(BSZ), 256, 0, stream>>>(0, t, gi0, gh, h_f32, h_bf, X_all, ln_s, ln_b);
        k_gemm_f32<<<dim3(B3H / 64, BSZ / 64), 256, 0, stream>>>(h_bf, HID,
                   Wih_bf + (size_t)1 * B3H * HID, HID, gbih + 1 * B3H, giX, B3H, HID);
        k_ew<<<dim3(BSZ), 256, 0, stream>>>(1, t, giX, gh, h_f32, h_bf, X_all, ln_s, ln_b);
        k_gemm_f32<<<dim3(B3H / 64, BSZ / 64), 256, 0, stream>>>(h_bf + (size_t)BSZ * HID, HID,
                   Wih_bf + (size_t)2 * B3H * HID, HID, gbih + 2 * B3H, giX, B3H, HID);
        k_ew<<<dim3(BSZ), 256, 0, stream>>>(2, t, giX, gh, h_f32, h_bf, X_all, ln_s, ln_b);
        k_fc1<<<dim3(2048 / 64, BSZ / 64), 256, 0, stream>>>(h_bf + (size_t)2 * BSZ * HID,
                                                             fc1W_bf, fc1b, a1_bf);
        k_fc2<<<dim3(VOC / 64, BSZ / 64, 8), 256, 0, stream>>>(a1_bf, fc2W_bf, part);
        k_lse<<<dim3(BSZ / 4), 256, 0, stream>>>(part, fc2b, target, t, accbuf, out);
    }
}

// Round 2
// 16235.823 us; speedup vs baseline: 1.1941x; 1.1941x over previous
//
#include <hip/hip_runtime.h>
#include <stdint.h>

// ---------------- constants ----------------
#define HID   1024          // H
#define B3H   3072          // 3H
#define BSZ   256           // batch
#define TLEN  128           // seq len
#define VOC   512
#define EMB   512

typedef unsigned short u16;
typedef short bf16x8 __attribute__((ext_vector_type(8)));
typedef float f32x4  __attribute__((ext_vector_type(4)));

__device__ __forceinline__ float bf2f(u16 u) {
    union { float f; uint32_t i; } c; c.i = ((uint32_t)u) << 16; return c.f;
}
__device__ __forceinline__ u16 f2bf(float f) {
    union { float f; uint32_t i; } c; c.f = f;
    uint32_t u = c.i;
    return (u16)((u + 0x7FFFu + ((u >> 16) & 1u)) >> 16);   // RNE
}
__device__ __forceinline__ float sigm(float x)  { return 1.f / (1.f + __expf(-x)); }
__device__ __forceinline__ float tanhf_(float x) {
    float e = __expf(-2.f * fabsf(x));
    float r = (1.f - e) / (1.f + e);
    return x < 0.f ? -r : r;
}

// ---------------- tiny utility kernels ----------------
__global__ void k_convert(const float* __restrict__ in, u16* __restrict__ out, int n) {
    int i = (blockIdx.x * 256 + threadIdx.x) * 4;
    if (i >= n) return;
    float4 f = *(const float4*)(in + i);
    uint32_t lo = (uint32_t)f2bf(f.x) | ((uint32_t)f2bf(f.y) << 16);
    uint32_t hi = (uint32_t)f2bf(f.z) | ((uint32_t)f2bf(f.w) << 16);
    uint2 p; p.x = lo; p.y = hi;
    *(uint2*)(out + i) = p;
}
__global__ void k_zero_f32(float* p, int n) { int i = blockIdx.x * 256 + threadIdx.x; if (i < n) p[i] = 0.f; }
__global__ void k_zero_u16(u16* p, int n)   { int i = blockIdx.x * 256 + threadIdx.x; if (i < n) p[i] = 0;   }

// ---------------- MFMA tile helpers ----------------
// Wave computes a 16(M) x 64(N) strip.  A/W row-major bf16, C = A @ W^T.
// D frag: col = lane&15, row = (lane>>4)*4 + reg   [m89-verified]
template<int KLEN>
__device__ __forceinline__ void mfma16x64(const u16* __restrict__ Aw, int lda,
                                          const u16* __restrict__ Wt, int ldb,
                                          f32x4 acc[4], int lane) {
    const int r = lane & 15, g = lane >> 4;
    const u16* ap = Aw + (size_t)r * lda + g * 8;
    const u16* bp = Wt + (size_t)r * ldb + g * 8;
#pragma unroll 4
    for (int k = 0; k < KLEN; k += 32) {
        bf16x8 a = *(const bf16x8*)(ap + k);
#pragma unroll
        for (int n = 0; n < 4; n++) {
            bf16x8 b = *(const bf16x8*)(bp + (size_t)(n * 16) * ldb + k);
            acc[n] = __builtin_amdgcn_mfma_f32_16x16x32_bf16(a, b, acc[n], 0, 0, 0);
        }
    }
}
__device__ __forceinline__ void store_f32(float* Cw, int ldc, const float* bias,
                                          const f32x4 acc[4], int lane) {
    int c = lane & 15, r0 = (lane >> 4) * 4;
#pragma unroll
    for (int n = 0; n < 4; n++)
#pragma unroll
        for (int r = 0; r < 4; r++) {
            float x = acc[n][r] + (bias ? bias[n * 16 + c] : 0.f);
            Cw[(size_t)(r0 + r) * ldc + n * 16 + c] = x;
        }
}

// ---------------- proj: X_all[t*B+b] = emb[tok] @ projW^T + projb (bf16 out) ----------------
__global__ void __launch_bounds__(256) k_proj(const u16* __restrict__ emb_bf, const u16* __restrict__ projW_bf,
                       const float* __restrict__ projb, const int* __restrict__ target,
                       u16* __restrict__ X_all) {
    int tn = blockIdx.x * 64, tm = blockIdx.y * 64;
    int wid = threadIdx.x >> 6, lane = threadIdx.x & 63;
    int rr = lane & 15, g = lane >> 4;
    int rowg = tm + wid * 16 + rr;
    int t = rowg >> 8, b = rowg & 255;
    int tok = (t == 0) ? 0 : target[b * TLEN + t - 1];
    const u16* ap = emb_bf + (size_t)tok * EMB + g * 8;
    f32x4 acc[4];
#pragma unroll
    for (int n = 0; n < 4; n++) for (int q = 0; q < 4; q++) acc[n][q] = 0.f;
#pragma unroll 4
    for (int k = 0; k < EMB; k += 32) {
        bf16x8 a = *(const bf16x8*)(ap + k);
#pragma unroll
        for (int n = 0; n < 4; n++) {
            bf16x8 bb = *(const bf16x8*)(projW_bf + (size_t)(tn + n * 16 + rr) * EMB + g * 8 + k);
            acc[n] = __builtin_amdgcn_mfma_f32_16x16x32_bf16(a, bb, acc[n], 0, 0, 0);
        }
    }
    int c = lane & 15, r0 = (lane >> 4) * 4;
    u16* Cw = X_all + (size_t)(tm + wid * 16) * HID + tn;
#pragma unroll
    for (int n = 0; n < 4; n++)
#pragma unroll
        for (int q = 0; q < 4; q++)
            Cw[(size_t)(r0 + q) * HID + n * 16 + c] = f2bf(acc[n][q] + projb[tn + n * 16 + c]);
}

// ---------------- gates: gi0 + gh0..gh2 (4 GEMMs, no bias — added in ew) ----------------
__global__ void __launch_bounds__(256) k_gates(const u16* __restrict__ X_all, const u16* __restrict__ h_bf,
                        const u16* __restrict__ Wih, const u16* __restrict__ Whh,
                        float* __restrict__ gi0, float* __restrict__ gh, int t) {
    int z = blockIdx.z;
    const u16* A; const u16* W; float* C;
    if (z == 0) { A = X_all + (size_t)t * BSZ * HID; W = Wih; C = gi0; }
    else {
        int i = z - 1;
        A = h_bf + (size_t)i * BSZ * HID;
        W = Whh + (size_t)i * B3H * HID;
        C = gh + (size_t)i * BSZ * B3H;
    }
    int tn = blockIdx.x * 64, tm = blockIdx.y * 64;
    int wid = threadIdx.x >> 6, lane = threadIdx.x & 63;
    f32x4 acc[4];
#pragma unroll
    for (int n = 0; n < 4; n++) for (int q = 0; q < 4; q++) acc[n][q] = 0.f;
    mfma16x64<HID>(A + (size_t)(tm + wid * 16) * HID, HID, W + (size_t)tn * HID, HID, acc, lane);
    store_f32(C + (size_t)(tm + wid * 16) * B3H + tn, B3H, nullptr, acc, lane);
}

// ---------------- gi for cell 1/2, K-split KS ways: giP[kc][B][3H] ----------------
template<int KCH>
__global__ void __launch_bounds__(256) k_giX(const u16* __restrict__ A, const u16* __restrict__ W,
                                             float* __restrict__ giP) {
    int kc = blockIdx.z;
    int tn = blockIdx.x * 64, tm = blockIdx.y * 64;
    int wid = threadIdx.x >> 6, lane = threadIdx.x & 63;
    f32x4 acc[4];
#pragma unroll
    for (int n = 0; n < 4; n++) for (int q = 0; q < 4; q++) acc[n][q] = 0.f;
    mfma16x64<KCH>(A + (size_t)(tm + wid * 16) * HID + kc * KCH, HID,
                   W + (size_t)tn * HID + kc * KCH, HID, acc, lane);
    store_f32(giP + (size_t)kc * BSZ * B3H + (size_t)(tm + wid * 16) * B3H + tn, B3H, nullptr, acc, lane);
}

// ---------------- GRU elementwise + residual + LayerNorm (one WG per row) ----------------
__global__ void __launch_bounds__(256) k_ew(int cell, int t,
                     const float* __restrict__ giP, int giKS,
                     const float* __restrict__ gh_all,
                     const float* __restrict__ bih_all, const float* __restrict__ bhh_all,
                     float* __restrict__ h_f32, u16* __restrict__ h_bf,
                     u16* __restrict__ X_all,
                     const float* __restrict__ ln_s_all, const float* __restrict__ ln_b_all) {
    int b = blockIdx.x, tid = threadIdx.x;
    int j0 = tid * 4;
    const float* ghr = gh_all + ((size_t)cell * BSZ + b) * B3H;
    const float* bih = bih_all + cell * B3H;
    const float* bhh = bhh_all + cell * B3H;
    float gi[3][4], gh[3][4];
#pragma unroll
    for (int g = 0; g < 3; g++) {
        int base = g * HID + j0;
        float4 a = *(const float4*)(bih + base);
        for (int kc = 0; kc < giKS; kc++) {
            float4 p = *(const float4*)(giP + (size_t)kc * BSZ * B3H + (size_t)b * B3H + base);
            a.x += p.x; a.y += p.y; a.z += p.z; a.w += p.w;
        }
        gi[g][0] = a.x; gi[g][1] = a.y; gi[g][2] = a.z; gi[g][3] = a.w;
        float4 hg = *(const float4*)(ghr + base);
        float4 bb = *(const float4*)(bhh + base);
        gh[g][0] = hg.x + bb.x; gh[g][1] = hg.y + bb.y; gh[g][2] = hg.z + bb.z; gh[g][3] = hg.w + bb.w;
    }
    float hp[4];
    *(float4*)hp = *(const float4*)(h_f32 + ((size_t)cell * BSZ + b) * HID + j0);
    float xv[4];
    if (cell == 0) {
        ushort4 u = *(const ushort4*)(X_all + ((size_t)t * BSZ + b) * HID + j0);
        xv[0] = bf2f(u.x); xv[1] = bf2f(u.y); xv[2] = bf2f(u.z); xv[3] = bf2f(u.w);
    } else {
        *(float4*)xv = *(const float4*)(h_f32 + ((size_t)(cell - 1) * BSZ + b) * HID + j0);
    }
    float val[4], s = 0.f, s2 = 0.f;
#pragma unroll
    for (int q = 0; q < 4; q++) {
        float r = sigm(gi[0][q] + gh[0][q]);
        float z = sigm(gi[1][q] + gh[1][q]);
        float n = tanhf_(gi[2][q] + r * gh[2][q]);
        float v = (1.f - z) * n + z * hp[q] + xv[q];
        val[q] = v; s += v; s2 += v * v;
    }
    __shared__ float red[8];
    for (int o = 32; o > 0; o >>= 1) { s += __shfl_down(s, o); s2 += __shfl_down(s2, o); }
    int wid = tid >> 6, lane = tid & 63;
    if (lane == 0) { red[wid] = s; red[4 + wid] = s2; }
    __syncthreads();
    s = red[0] + red[1] + red[2] + red[3];
    s2 = red[4] + red[5] + red[6] + red[7];
    float mu = s * (1.f / HID);
    float var = s2 * (1.f / HID) - mu * mu;
    float inv = rsqrtf(var + 1e-5f);
    float4 lns = *(const float4*)(ln_s_all + cell * HID + j0);
    float4 lnb = *(const float4*)(ln_b_all + cell * HID + j0);
    float o0 = (val[0] - mu) * inv * lns.x + lnb.x;
    float o1 = (val[1] - mu) * inv * lns.y + lnb.y;
    float o2 = (val[2] - mu) * inv * lns.z + lnb.z;
    float o3 = (val[3] - mu) * inv * lns.w + lnb.w;
    float4 of; of.x = o0; of.y = o1; of.z = o2; of.w = o3;
    *(float4*)(h_f32 + ((size_t)cell * BSZ + b) * HID + j0) = of;
    ushort4 ob; ob.x = f2bf(o0); ob.y = f2bf(o1); ob.z = f2bf(o2); ob.w = f2bf(o3);
    *(ushort4*)(h_bf + ((size_t)cell * BSZ + b) * HID + j0) = ob;
    if (cell == 2)
        *(ushort4*)(X_all + ((size_t)t * BSZ + b) * HID + j0) = ob;   // slot t consumed; reuse as H2_all
}

// ---------------- batched tail: fc1 (relu, bf16 out) ----------------
__global__ void __launch_bounds__(256) k_fc1b(const u16* __restrict__ A, const u16* __restrict__ W,
                       const float* __restrict__ bias, u16* __restrict__ C) {
    int tn = blockIdx.x * 64, tm = blockIdx.y * 64;
    int wid = threadIdx.x >> 6, lane = threadIdx.x & 63;
    f32x4 acc[4];
#pragma unroll
    for (int n = 0; n < 4; n++) for (int q = 0; q < 4; q++) acc[n][q] = 0.f;
    mfma16x64<HID>(A + (size_t)(tm + wid * 16) * HID, HID, W + (size_t)tn * HID, HID, acc, lane);
    int c = lane & 15, r0 = (lane >> 4) * 4;
    u16* Cw = C + (size_t)(tm + wid * 16) * 2048 + tn;
#pragma unroll
    for (int n = 0; n < 4; n++)
#pragma unroll
        for (int q = 0; q < 4; q++) {
            float x = acc[n][q] + bias[tn + n * 16 + c];
            Cw[(size_t)(r0 + q) * 2048 + n * 16 + c] = f2bf(fmaxf(x, 0.f));
        }
}

// ---------------- batched tail: fc2 (+bias, f32 out) ----------------
__global__ void __launch_bounds__(256) k_fc2b(const u16* __restrict__ A, const u16* __restrict__ W,
                       const float* __restrict__ bias, float* __restrict__ C) {
    int tn = blockIdx.x * 64, tm = blockIdx.y * 64;
    int wid = threadIdx.x >> 6, lane = threadIdx.x & 63;
    f32x4 acc[4];
#pragma unroll
    for (int n = 0; n < 4; n++) for (int q = 0; q < 4; q++) acc[n][q] = 0.f;
    mfma16x64<2048>(A + (size_t)(tm + wid * 16) * 2048, 2048, W + (size_t)tn * 2048, 2048, acc, lane);
    store_f32(C + (size_t)(tm + wid * 16) * VOC + tn, VOC, bias + tn, acc, lane);
}

// ---------------- logsumexp + target gather -> LP[t][b] ----------------
__global__ void __launch_bounds__(256) k_lse2(const float* __restrict__ part, const int* __restrict__ target,
                       int c0, float* __restrict__ LP) {
    int wid = threadIdx.x >> 6, lane = threadIdx.x & 63;
    int r = blockIdx.x * 4 + wid;
    const float* row = part + (size_t)r * VOC;
    float v[8];
#pragma unroll
    for (int e = 0; e < 8; e++) v[e] = row[e * 64 + lane];
    float m = v[0];
#pragma unroll
    for (int e = 1; e < 8; e++) m = fmaxf(m, v[e]);
    for (int o = 32; o > 0; o >>= 1) m = fmaxf(m, __shfl_xor(m, o));
    float s = 0.f;
#pragma unroll
    for (int e = 0; e < 8; e++) s += __expf(v[e] - m);
    for (int o = 32; o > 0; o >>= 1) s += __shfl_xor(s, o);
    int t = c0 + (r >> 8), b = r & 255;
    int tg = target[b * TLEN + t];
    float tv = 0.f;
#pragma unroll
    for (int e = 0; e < 8; e++) if (e * 64 + lane == tg) tv = v[e];
    for (int o = 32; o > 0; o >>= 1) tv += __shfl_xor(tv, o);
    if (lane == 0) LP[(size_t)t * BSZ + b] = tv - (m + logf(s));
}

// ---------------- final: out[b] = sum_t LP[t][b] ----------------
__global__ void k_out(const float* __restrict__ LP, float* __restrict__ out) {
    int b = threadIdx.x;
    float s = 0.f;
    for (int t = 0; t < TLEN; t++) s += LP[(size_t)t * BSZ + b];
    out[b] = s;
}

// ---------------- host ----------------
extern "C" void kernel_launch(void* const* d_in, const int* in_sizes, int n_in,
                              void* d_out, int out_size, void* d_ws, size_t ws_size,
                              hipStream_t stream) {
    const int*   target = (const int*)  d_in[0];
    const float* emb    = (const float*)d_in[1];
    const float* projW  = (const float*)d_in[2];
    const float* projb  = (const float*)d_in[3];
    const float* gWih   = (const float*)d_in[4];
    const float* gWhh   = (const float*)d_in[5];
    const float* gbih   = (const float*)d_in[6];
    const float* gbhh   = (const float*)d_in[7];
    const float* ln_s   = (const float*)d_in[8];
    const float* ln_b   = (const float*)d_in[9];
    const float* fc1W   = (const float*)d_in[10];
    const float* fc1b   = (const float*)d_in[11];
    const float* fc2W   = (const float*)d_in[12];
    const float* fc2b   = (const float*)d_in[13];
    float* out = (float*)d_out;

    char* ws = (char*)d_ws;
    size_t off = 0;
    auto alloc = [&](size_t bytes) { void* p = ws + off; off += (bytes + 511) & ~511ull; return p; };
    u16* emb_bf   = (u16*)alloc((size_t)VOC * EMB * 2);
    u16* projW_bf = (u16*)alloc((size_t)HID * EMB * 2);
    u16* Wih_bf   = (u16*)alloc((size_t)3 * B3H * HID * 2);
    u16* Whh_bf   = (u16*)alloc((size_t)3 * B3H * HID * 2);
    u16* fc1W_bf  = (u16*)alloc((size_t)2048 * HID * 2);
    u16* fc2W_bf  = (u16*)alloc((size_t)VOC * 2048 * 2);
    u16* X_all    = (u16*)alloc((size_t)TLEN * BSZ * HID * 2);   // reused as H2_all after consumption
    float* h_f32  = (float*)alloc((size_t)3 * BSZ * HID * 4);
    u16* h_bf     = (u16*)alloc((size_t)3 * BSZ * HID * 2);
    float* LP     = (float*)alloc((size_t)TLEN * BSZ * 4);

    // K-split config chosen from ws_size (deterministic across calls)
    size_t rem = (ws_size > off) ? ws_size - off : 0;
    const size_t MB = 1ull << 20;
    int KS = (rem >= 25 * MB) ? 4 : 2;       // giXp = KS*3MB ; region = 12 + 3*KS MB
    int CH = (KS == 4) ? 16 : 8;             // tail chunk (1.5*CH MB overlays region)

    float* gi0  = (float*)alloc((size_t)BSZ * B3H * 4);                 // 3 MB
    float* gh   = (float*)alloc((size_t)3 * BSZ * B3H * 4);             // 9 MB
    float* giXp = (float*)alloc((size_t)KS * BSZ * B3H * 4);            // KS*3 MB
    if (off > ws_size) return;

    // tail overlays the (then-dead) loop partial region
    u16*   a1c   = (u16*)gi0;                                           // CH MB
    float* partc = (float*)((char*)gi0 + (size_t)CH * BSZ * 2048 * 2);  // CH/2 MB

    auto cvt = [&](const float* s, u16* d, int n) {
        k_convert<<<dim3((n / 4 + 255) / 256), 256, 0, stream>>>(s, d, n);
    };
    cvt(emb,   emb_bf,   VOC * EMB);
    cvt(projW, projW_bf, HID * EMB);
    cvt(gWih,  Wih_bf,   3 * B3H * HID);
    cvt(gWhh,  Whh_bf,   3 * B3H * HID);
    cvt(fc1W,  fc1W_bf,  2048 * HID);
    cvt(fc2W,  fc2W_bf,  VOC * 2048);
    k_zero_f32<<<dim3((3 * BSZ * HID + 255) / 256), 256, 0, stream>>>(h_f32, 3 * BSZ * HID);
    k_zero_u16<<<dim3((3 * BSZ * HID + 255) / 256), 256, 0, stream>>>(h_bf, 3 * BSZ * HID);

    // X_all[t*B+b] = emb[tok] @ projW^T + projb
    k_proj<<<dim3(HID / 64, (TLEN * BSZ) / 64), 256, 0, stream>>>(emb_bf, projW_bf, projb, target, X_all);

    for (int t = 0; t < TLEN; t++) {
        k_gates<<<dim3(B3H / 64, BSZ / 64, 4), 256, 0, stream>>>(X_all, h_bf, Wih_bf, Whh_bf, gi0, gh, t);
        k_ew<<<dim3(BSZ), 256, 0, stream>>>(0, t, gi0, 1, gh, gbih, gbhh, h_f32, h_bf, X_all, ln_s, ln_b);
        if (KS == 4)
            k_giX<256><<<dim3(B3H / 64, BSZ / 64, 4), 256, 0, stream>>>(h_bf, Wih_bf + (size_t)1 * B3H * HID, giXp);
        else
            k_giX<512><<<dim3(B3H / 64, BSZ / 64, 2), 256, 0, stream>>>(h_bf, Wih_bf + (size_t)1 * B3H * HID, giXp);
        k_ew<<<dim3(BSZ), 256, 0, stream>>>(1, t, giXp, KS, gh, gbih, gbhh, h_f32, h_bf, X_all, ln_s, ln_b);
        if (KS == 4)
            k_giX<256><<<dim3(B3H / 64, BSZ / 64, 4), 256, 0, stream>>>(h_bf + (size_t)BSZ * HID,
                                                                        Wih_bf + (size_t)2 * B3H * HID, giXp);
        else
            k_giX<512><<<dim3(B3H / 64, BSZ / 64, 2), 256, 0, stream>>>(h_bf + (size_t)BSZ * HID,
                                                                        Wih_bf + (size_t)2 * B3H * HID, giXp);
        k_ew<<<dim3(BSZ), 256, 0, stream>>>(2, t, giXp, KS, gh, gbih, gbhh, h_f32, h_bf, X_all, ln_s, ln_b);
    }

    // batched tail over T in chunks: fc1 -> fc2 -> log-softmax
    for (int c0 = 0; c0 < TLEN; c0 += CH) {
        int M = CH * BSZ;
        const u16* Ain = X_all + (size_t)c0 * BSZ * HID;   // H2 rows for steps [c0, c0+CH)
        k_fc1b<<<dim3(2048 / 64, M / 64), 256, 0, stream>>>(Ain, fc1W_bf, fc1b, a1c);
        k_fc2b<<<dim3(VOC / 64, M / 64), 256, 0, stream>>>(a1c, fc2W_bf, fc2b, partc);
        k_lse2<<<dim3(M / 4), 256, 0, stream>>>(partc, target, c0, LP);
    }
    k_out<<<1, 256, 0, stream>>>(LP, out);
}